// Round 5
// baseline (625.338 us; speedup 1.0000x reference)
//
#include <hip/hip_runtime.h>
#include <stdint.h>

#define BB 16
#define SS 2048
#define FF 512
#define DD 128
#define CC 1000

typedef __attribute__((ext_vector_type(8))) short bf16x8;
typedef __attribute__((ext_vector_type(4))) float f32x4;

__device__ __forceinline__ unsigned short f2bf(float f) {
  unsigned x;
  __builtin_memcpy(&x, &f, 4);
  x = x + 0x7FFFu + ((x >> 16) & 1u);
  return (unsigned short)(x >> 16);
}
__device__ __forceinline__ float bf2f(unsigned short u) {
  unsigned x = ((unsigned)u) << 16;
  float f;
  __builtin_memcpy(&f, &x, 4);
  return f;
}
__device__ __forceinline__ unsigned pk2(float a, float b) {
  return (unsigned)f2bf(a) | ((unsigned)f2bf(b) << 16);
}

// ---- workspace layout (bytes) ----
#define WS_PK   0          // packed mask bits uint32 [B][S][64] (8 MB)
#define WS_Q    8388608    // bf16 [B][S][128], q pre-scaled by D^-0.5
#define WS_K    16777216
#define WS_V    25165824
#define WS_WT   33554432   // bf16 WT[3][128][512]
#define WS_WGP  33947648   // float wgp[B][64 rowgroups][2048] partial colsums (8 MB)
#define WS_END  42336256

// ---------------- prep: mask probe (per-block) + mask pack + W transpose ----------------
__global__ __launch_bounds__(256) void k_prep(const void* __restrict__ mask,
                                              const float* __restrict__ Wq,
                                              const float* __restrict__ Wk,
                                              const float* __restrict__ Wv,
                                              unsigned short* __restrict__ wt,
                                              unsigned* __restrict__ pk) {
  __shared__ unsigned red;
  const int tid = threadIdx.x;
  if (tid == 0) red = 0;
  __syncthreads();
  {  // probe the global mask head (4 KB): int32 masks never set bits 8..31
    unsigned a = 0;
    const unsigned* m32 = (const unsigned*)mask;
#pragma unroll
    for (int j = 0; j < 4; ++j) a |= m32[tid * 4 + j] & 0xFFFFFF00u;
    if (a) atomicOr(&red, 1u);
  }
  __syncthreads();
  const bool isInt = (red == 0);

  const long long base = (long long)blockIdx.x * 32768;
  for (int it = 0; it < 128; ++it) {
    long long e = base + it * 256 + tid;
    int val;
    if (isInt) val = ((const int*)mask)[e];
    else       val = ((const unsigned char*)mask)[e];
    unsigned long long bal = __ballot(val != 0);
    if ((tid & 31) == 0)
      pk[e >> 5] = (unsigned)((tid & 63) ? (bal >> 32) : bal);
  }

  if (blockIdx.x < 768) {
    int idx = blockIdx.x * 256 + tid;
    int ty = idx >> 16;
    int o = idx & 65535;
    int d = o >> 9, f = o & 511;
    const float* W = ty == 0 ? Wq : (ty == 1 ? Wk : Wv);
    wt[idx] = f2bf(W[f * DD + d]);
  }
}

// ---------------- QKV projection: x LDS-resident, 3 outputs per block ----------------
// 256 blocks of 128 rows. xA = [128][512] bf16 (128 KB), chunk-swizzled
// c ^ (row & 63). Per ty: 16 K-chunks, lB re-staged (proven layout).
__global__ __launch_bounds__(256) void k_proj(const float* __restrict__ xg,
                                              const unsigned short* __restrict__ wtg,
                                              const float* __restrict__ bq,
                                              const float* __restrict__ bk,
                                              const float* __restrict__ bv,
                                              unsigned short* __restrict__ qo,
                                              unsigned short* __restrict__ ko,
                                              unsigned short* __restrict__ vo) {
  extern __shared__ __align__(16) char smem[];
  char* xA = smem;                 // 131072 B
  char* lB = smem + 131072;        // 8192 B
  const int tid = threadIdx.x;
  const int lane = tid & 63;
  const int wv = tid >> 6;
  const int colL = lane & 15, quad = lane >> 4;
  const int blk = blockIdx.x;
  const int m0 = (wv & 1) * 64, n0 = (wv >> 1) * 64;

  // stage x resident: 8192 chunks of 16B, 32 iters
#pragma unroll 4
  for (int it = 0; it < 32; ++it) {
    int id = it * 256 + tid;
    int row = id >> 6, c = id & 63;
    const float* xp = xg + (size_t)(blk * 128 + row) * FF + c * 8;
    float4 x0 = *(const float4*)xp;
    float4 x1 = *(const float4*)(xp + 4);
    uint4 w;
    w.x = pk2(x0.x, x0.y); w.y = pk2(x0.z, x0.w);
    w.z = pk2(x1.x, x1.y); w.w = pk2(x1.z, x1.w);
    *(uint4*)(xA + row * 1024 + (c ^ (row & 63)) * 16) = w;
  }

  for (int ty = 0; ty < 3; ++ty) {
    const float* bias = ty == 0 ? bq : (ty == 1 ? bk : bv);
    unsigned short* outp = ty == 0 ? qo : (ty == 1 ? ko : vo);
    const float scale = ty == 0 ? 0.08838834764831845f : 1.0f;
    const unsigned short* wbase = wtg + (size_t)ty * 65536;

    f32x4 acc[4][4];
    const f32x4 z4 = {0.f, 0.f, 0.f, 0.f};
#pragma unroll
    for (int mi = 0; mi < 4; ++mi)
#pragma unroll
      for (int ni = 0; ni < 4; ++ni) acc[mi][ni] = z4;

    for (int ic = 0; ic < 16; ++ic) {
      const int k0 = ic * 32;
      uint4 vb[2];
#pragma unroll
      for (int rr = 0; rr < 2; ++rr) {
        int p = rr * 256 + tid;
        int row = p >> 2, c = p & 3;
        vb[rr] = *(const uint4*)(wbase + (size_t)row * FF + k0 + c * 8);
      }
      __syncthreads();   // prior lB reads done (ic=0,ty=0: xA staging also done)
#pragma unroll
      for (int rr = 0; rr < 2; ++rr) {
        int p = rr * 256 + tid;
        int row = p >> 2, c = p & 3;
        int phys = c ^ ((row >> 1) & 3);
        *(uint4*)(lB + row * 64 + phys * 16) = vb[rr];
      }
      __syncthreads();
      bf16x8 af[4], bfr[4];
#pragma unroll
      for (int mi = 0; mi < 4; ++mi) {
        int ar = m0 + mi * 16 + colL;
        int cch = ic * 4 + quad;
        int phys = cch ^ (ar & 63);
        af[mi] = *(const bf16x8*)(xA + ar * 1024 + phys * 16);
      }
#pragma unroll
      for (int ni = 0; ni < 4; ++ni) {
        int br = n0 + ni * 16 + colL;
        int phys = quad ^ ((br >> 1) & 3);
        bfr[ni] = *(const bf16x8*)(lB + br * 64 + phys * 16);
      }
#pragma unroll
      for (int mi = 0; mi < 4; ++mi)
#pragma unroll
        for (int ni = 0; ni < 4; ++ni)
          acc[mi][ni] = __builtin_amdgcn_mfma_f32_16x16x32_bf16(af[mi], bfr[ni], acc[mi][ni], 0, 0, 0);
    }
#pragma unroll
    for (int ni = 0; ni < 4; ++ni) {
      int col = n0 + ni * 16 + colL;
      float bval = bias[col];
#pragma unroll
      for (int mi = 0; mi < 4; ++mi) {
#pragma unroll
        for (int r = 0; r < 4; ++r) {
          int row = blk * 128 + m0 + mi * 16 + quad * 4 + r;
          float val = (acc[mi][ni][r] + bval) * scale;
          outp[(size_t)row * DD + col] = f2bf(val);
        }
      }
    }
  }
}

// ---------------- fused attention: P kept in REGISTERS ----------------
// Block = (32 q-rows, batch b), 512 thr = 8 waves (wr row-half, wq t-quarter).
// Per chunk each lane's C-fragment = 4 rows x 1 t -> e packed bf16x2 into
// estore[64] VGPRs. After Z: unpack, *zinv, shfl-reduce over quad, ds_add
// into wacc[2048], vectorized store to wgp. kt double-buffered, 1 barrier/chunk.
__global__ __launch_bounds__(512, 2) void k_fatt(const unsigned short* __restrict__ qg,
                                                 const unsigned short* __restrict__ kg,
                                                 const unsigned* __restrict__ pk,
                                                 float* __restrict__ wgp) {
  __shared__ __align__(16) char kt[32768];     // 2 x [64][256B], swizzle c^(r&7)
  __shared__ unsigned mk[32 * 65];             // mask words
  __shared__ float wacc[2048];
  __shared__ float zfin[32];
  __shared__ float zinvl[32];

  const int tid = threadIdx.x;
  const int lane = tid & 63, wv = tid >> 6;
  const int colL = lane & 15, quad = lane >> 4;
  const int wr = wv & 1, wq = wv >> 1;
  const int r0 = blockIdx.x * 32;
  const int b = blockIdx.y;

  for (int i = tid; i < 2048; i += 512) {
    int row = i >> 6, w = i & 63;
    mk[row * 65 + w] = pk[((size_t)b * SS + r0 + row) * 64 + w];
    wacc[i] = 0.f;
  }
  if (tid < 32) zfin[tid] = 0.f;

  bf16x8 qf[4];
  {
    int qrow = r0 + wr * 16 + colL;
    const unsigned short* qp = qg + ((size_t)b * SS + qrow) * DD + quad * 8;
#pragma unroll
    for (int kk = 0; kk < 4; ++kk) qf[kk] = *(const bf16x8*)(qp + kk * 32);
  }

  const int krow = tid >> 3, kc8 = tid & 7;
  const unsigned short* kbase = kg + ((size_t)b * SS + krow) * DD;
  const int kswz0 = (kc8 ^ (krow & 7)) * 16;
  const int kswz1 = ((kc8 + 8) ^ (krow & 7)) * 16;

  {
    uint4 k0r = *(const uint4*)(kbase + kc8 * 8);
    uint4 k1r = *(const uint4*)(kbase + kc8 * 8 + 64);
    *(uint4*)(kt + krow * 256 + kswz0) = k0r;
    *(uint4*)(kt + krow * 256 + kswz1) = k1r;
  }
  __syncthreads();   // kt buf0, mk, wacc-zero, zfin-zero visible

  float z[4] = {0.f, 0.f, 0.f, 0.f};
  unsigned estore[64];
  const int tb = wq * 16 + colL;

#pragma unroll
  for (int c = 0; c < 32; ++c) {
    uint4 k0r, k1r;
    if (c < 31) {
      const unsigned short* kb2 = kbase + (size_t)(c + 1) * 64 * DD;
      k0r = *(const uint4*)(kb2 + kc8 * 8);
      k1r = *(const uint4*)(kb2 + kc8 * 8 + 64);
    }
    const char* ktb = kt + (c & 1) * 16384;
    bf16x8 bb[4];
#pragma unroll
    for (int kk = 0; kk < 4; ++kk) {
      int phys = (kk * 4 + quad) ^ (tb & 7);
      bb[kk] = *(const bf16x8*)(ktb + tb * 256 + phys * 16);
    }
    f32x4 acc = {0.f, 0.f, 0.f, 0.f};
    acc = __builtin_amdgcn_mfma_f32_16x16x32_bf16(qf[0], bb[0], acc, 0, 0, 0);
    acc = __builtin_amdgcn_mfma_f32_16x16x32_bf16(qf[1], bb[1], acc, 0, 0, 0);
    acc = __builtin_amdgcn_mfma_f32_16x16x32_bf16(qf[2], bb[2], acc, 0, 0, 0);
    acc = __builtin_amdgcn_mfma_f32_16x16x32_bf16(qf[3], bb[3], acc, 0, 0, 0);
    const int tl = c * 64 + tb;
    const int widx = tl >> 5, wb = tl & 31;
    const int rbase = wr * 16 + quad * 4;
    float e0, e1, e2, e3;
    {
      unsigned mw0 = mk[(rbase + 0) * 65 + widx];
      unsigned mw1 = mk[(rbase + 1) * 65 + widx];
      unsigned mw2 = mk[(rbase + 2) * 65 + widx];
      unsigned mw3 = mk[(rbase + 3) * 65 + widx];
      e0 = ((mw0 >> wb) & 1u) ? 0.f : __expf(fminf(acc[0], 80.f));
      e1 = ((mw1 >> wb) & 1u) ? 0.f : __expf(fminf(acc[1], 80.f));
      e2 = ((mw2 >> wb) & 1u) ? 0.f : __expf(fminf(acc[2], 80.f));
      e3 = ((mw3 >> wb) & 1u) ? 0.f : __expf(fminf(acc[3], 80.f));
    }
    z[0] += e0; z[1] += e1; z[2] += e2; z[3] += e3;
    estore[c * 2]     = pk2(e0, e1);
    estore[c * 2 + 1] = pk2(e2, e3);
    if (c < 31) {
      char* ktn = kt + ((c + 1) & 1) * 16384;
      *(uint4*)(ktn + krow * 256 + kswz0) = k0r;
      *(uint4*)(ktn + krow * 256 + kswz1) = k1r;
      __syncthreads();   // buf(c+1) visible; all buf(c) reads done
    }
  }

  // Z: reduce over the 16 t-lanes (colL bits), accumulate across wq waves
#pragma unroll
  for (int r = 0; r < 4; ++r) {
    float s = z[r];
    s += __shfl_xor(s, 1, 64);
    s += __shfl_xor(s, 2, 64);
    s += __shfl_xor(s, 4, 64);
    s += __shfl_xor(s, 8, 64);
    if (colL == 0) atomicAdd(&zfin[wr * 16 + quad * 4 + r], s);
  }
  __syncthreads();
  if (tid < 32) zinvl[tid] = 1.0f / fmaxf(zfin[tid], 1e-30f);
  __syncthreads();

  // column-sum from registers: cs(c) = sum_r e_r * zinv_r, reduce over quad
  {
    f32x4 zi = *(const f32x4*)(zinvl + wr * 16 + quad * 4);
#pragma unroll
    for (int c = 0; c < 32; ++c) {
      unsigned u0 = estore[c * 2], u1 = estore[c * 2 + 1];
      float cs = bf2f((unsigned short)(u0 & 0xFFFFu)) * zi[0]
               + bf2f((unsigned short)(u0 >> 16))     * zi[1]
               + bf2f((unsigned short)(u1 & 0xFFFFu)) * zi[2]
               + bf2f((unsigned short)(u1 >> 16))     * zi[3];
      cs += __shfl_xor(cs, 16, 64);
      cs += __shfl_xor(cs, 32, 64);
      if (quad == 0) atomicAdd(&wacc[c * 64 + wq * 16 + colL], cs);
    }
  }
  __syncthreads();
  {
    const int t0 = tid * 4;
    float4 o4;
    o4.x = wacc[t0]; o4.y = wacc[t0 + 1]; o4.z = wacc[t0 + 2]; o4.w = wacc[t0 + 3];
    *(float4*)(wgp + ((size_t)b * 64 + blockIdx.x) * SS + t0) = o4;
  }
}

// ---------------- tail: wgp-reduce, y = w.V, out = (y/S)@Wl + bl ----------------
__global__ __launch_bounds__(1024) void k_tail(const float* __restrict__ wgp,
                                               const unsigned short* __restrict__ vg,
                                               const float* __restrict__ Wl,
                                               const float* __restrict__ bl,
                                               float* __restrict__ outp) {
  __shared__ float ws2[2048];
  __shared__ float yp[8][128];
  __shared__ float ys[128];
  const int tid = threadIdx.x;
  const int b = blockIdx.x;

  {
    float s0 = 0.f, s1 = 0.f;
    const float* wp = wgp + ((size_t)b * 64) * SS + tid * 2;
#pragma unroll 8
    for (int rg = 0; rg < 64; ++rg) {
      s0 += wp[rg * SS];
      s1 += wp[rg * SS + 1];
    }
    ws2[tid * 2] = s0;
    ws2[tid * 2 + 1] = s1;
  }
  __syncthreads();

  {
    const int d = tid & 127, tg = tid >> 7;
    const int t0 = tg * 256;
    float p = 0.f;
    const unsigned short* vr = vg + ((size_t)b * SS + t0) * DD + d;
#pragma unroll 8
    for (int t = 0; t < 256; ++t) p += ws2[t0 + t] * bf2f(vr[(size_t)t * DD]);
    yp[tg][d] = p;
  }
  __syncthreads();
  if (tid < 128) {
    float a = 0.f;
#pragma unroll
    for (int g = 0; g < 8; ++g) a += yp[g][tid];
    ys[tid] = a * (1.0f / 2048.0f);
  }
  __syncthreads();

  if (tid < CC) {
    float a = bl[tid];
#pragma unroll 16
    for (int dd = 0; dd < DD; ++dd) a += ys[dd] * Wl[dd * CC + tid];
    outp[b * CC + tid] = a;
  }
}

extern "C" void kernel_launch(void* const* d_in, const int* in_sizes, int n_in,
                              void* d_out, int out_size, void* d_ws, size_t ws_size,
                              hipStream_t stream) {
  const void* ptr[10];
  for (int i = 0; i < 10; ++i) ptr[i] = (i < n_in) ? d_in[i] : nullptr;
  if (n_in == 10) {  // size-based slot matching (no-op under dict order)
    const void *px = 0, *pm = 0, *pWl = 0, *pbl = 0;
    const void* pW[3] = {0, 0, 0};
    const void* pb[3] = {0, 0, 0};
    int nW = 0, nb = 0;
    for (int i = 0; i < 10; ++i) {
      int s = in_sizes[i];
      if (s == 16777216) px = d_in[i];
      else if (s == 67108864) pm = d_in[i];
      else if (s == 128000) pWl = d_in[i];
      else if (s == 1000) pbl = d_in[i];
      else if (s == 65536 && nW < 3) pW[nW++] = d_in[i];
      else if (s == 128 && nb < 3) pb[nb++] = d_in[i];
    }
    if (px && pm && pWl && pbl && nW == 3 && nb == 3) {
      ptr[0] = px; ptr[1] = pm;
      ptr[2] = pW[0]; ptr[3] = pb[0];
      ptr[4] = pW[1]; ptr[5] = pb[1];
      ptr[6] = pW[2]; ptr[7] = pb[2];
      ptr[8] = pWl; ptr[9] = pbl;
    }
  }
  char* ws = (char*)d_ws;
  if (ws_size < (size_t)WS_END) return;
  unsigned* pk = (unsigned*)(ws + WS_PK);
  unsigned short* q  = (unsigned short*)(ws + WS_Q);
  unsigned short* k  = (unsigned short*)(ws + WS_K);
  unsigned short* v  = (unsigned short*)(ws + WS_V);
  unsigned short* wt = (unsigned short*)(ws + WS_WT);
  float* wgp = (float*)(ws + WS_WGP);

  k_prep<<<2048, 256, 0, stream>>>(ptr[1], (const float*)ptr[2], (const float*)ptr[4],
                                   (const float*)ptr[6], wt, pk);
  k_proj<<<256, 256, 139264, stream>>>((const float*)ptr[0], wt,
                                       (const float*)ptr[3], (const float*)ptr[5],
                                       (const float*)ptr[7], q, k, v);
  k_fatt<<<dim3(64, 16), 512, 0, stream>>>(q, k, pk, wgp);
  k_tail<<<16, 1024, 0, stream>>>(wgp, v, (const float*)ptr[8], (const float*)ptr[9],
                                  (float*)d_out);
}